// Round 13
// baseline (66.610 us; speedup 1.0000x reference)
//
#include <hip/hip_runtime.h>

#define S_LEN 1024
#define D_DIM 64
#define NPOS 64

typedef float floatx4 __attribute__((ext_vector_type(4)));

__device__ __forceinline__ float sigmoid_fast(float x) {
    return __builtin_amdgcn_rcpf(1.0f + __expf(-x));
}

// f32 -> bf16 bits, round-to-nearest-even
__device__ __forceinline__ unsigned bf16_bits(float x) {
    unsigned u = __float_as_uint(x);
    return (u + 0x7fffu + ((u >> 16) & 1u)) >> 16;
}

// GEMV: logits[lane] = sum_d q[d]*pe[d][lane]; q uniform (s_loads), pe L1-resident.
// Returns packed bf16 pair (logits[lane], logits[lane+1]).
__device__ __forceinline__ int gemv_packed(const float* __restrict__ query,
                                           const float* __restrict__ pe,
                                           int urow, int lane) {
    const float* qrow = query + (size_t)urow * D_DIM;
    float a0 = 0.f, a1 = 0.f, a2 = 0.f, a3 = 0.f;
    #pragma unroll
    for (int d = 0; d < D_DIM; d += 4) {
        a0 = fmaf(qrow[d + 0], pe[(d + 0) * NPOS + lane], a0);
        a1 = fmaf(qrow[d + 1], pe[(d + 1) * NPOS + lane], a1);
        a2 = fmaf(qrow[d + 2], pe[(d + 2) * NPOS + lane], a2);
        a3 = fmaf(qrow[d + 3], pe[(d + 3) * NPOS + lane], a3);
    }
    float lreg = (a0 + a1) + (a2 + a3);
    float nb = __shfl_down(lreg, 1, 64);      // lane 63: undefined but w==0 there
    return (int)(bf16_bits(lreg) | (bf16_bits(nb) << 16));
}

// sigmoid -> suffix scan -> interp -> nt store for one row held in xv[4]
__device__ __forceinline__ void process_row(float4* xv, int packed,
                                            float* __restrict__ orow, int lane) {
    float s[4], I[4];
    #pragma unroll
    for (int k = 0; k < 4; ++k) {
        xv[k].x = sigmoid_fast(xv[k].x);
        xv[k].y = sigmoid_fast(xv[k].y);
        xv[k].z = sigmoid_fast(xv[k].z);
        xv[k].w = sigmoid_fast(xv[k].w);
        s[k] = (xv[k].x + xv[k].y) + (xv[k].z + xv[k].w);
    }
    #pragma unroll
    for (int k = 0; k < 4; ++k) {
        float v = s[k];
        #pragma unroll
        for (int off = 1; off < 64; off <<= 1) {
            float o = __shfl_down(v, off, 64);
            if (lane + off < 64) v += o;
        }
        I[k] = v;
    }
    float T1 = __shfl(I[1], 0, 64);
    float T2 = __shfl(I[2], 0, 64);
    float T3 = __shfl(I[3], 0, 64);
    float tail[4] = { T1 + T2 + T3, T2 + T3, T3, 0.f };

    #pragma unroll
    for (int k = 0; k < 4; ++k) {
        float after = (I[k] - s[k]) + tail[k];
        float p3 = xv[k].w + after;
        float p2 = xv[k].z + p3;
        float p1 = xv[k].y + p2;
        float p0 = xv[k].x + p1;
        float pv[4] = { p0, p1, p2, p3 };
        float o4[4];
        #pragma unroll
        for (int i = 0; i < 4; ++i) {
            float pc = fminf(pv[i], 63.0f);
            int   fi = (int)pc;
            float w  = pc - (float)fi;
            int  wrd = __shfl(packed, fi, 64);
            float lf = __uint_as_float((unsigned)wrd << 16);
            float lc = __uint_as_float((unsigned)wrd & 0xffff0000u);
            o4[i] = lc * w + lf * (1.0f - w);
        }
        floatx4 ov = { o4[0], o4[1], o4[2], o4[3] };
        __builtin_nontemporal_store(ov, reinterpret_cast<floatx4*>(orow + k * 256 + 4 * lane));
    }
}

__global__ __launch_bounds__(256) void cope_kernel(
    const float* __restrict__ attn,
    const float* __restrict__ query,
    const float* __restrict__ pe,     // [D_DIM][NPOS]
    float* __restrict__ out,
    int nrows)
{
    const int lane  = threadIdx.x & 63;
    const int gwave = blockIdx.x * 4 + (threadIdx.x >> 6);
    const int rowA  = gwave * 2;          // two adjacent rows per wave
    const int rowB  = rowA + 1;
    if (rowA >= nrows) return;
    const int urowA = __builtin_amdgcn_readfirstlane(rowA);
    const int urowB = __builtin_amdgcn_readfirstlane(rowB);
    const bool hasB = (rowB < nrows);

    // (1) issue row A's 4 coalesced 1KB loads
    const float* arowA = attn + (size_t)urowA * S_LEN;
    float4 xa[4];
    #pragma unroll
    for (int k = 0; k < 4; ++k)
        xa[k] = *reinterpret_cast<const float4*>(arowA + k * 256 + 4 * lane);

    // (2) GEMV A — its pe-load waits drain A's attn loads (needed next) but
    //     row B's loads are not yet issued, so nothing useful is drained.
    const int packedA = gemv_packed(query, pe, urowA, lane);

    // (3) issue row B's loads NOW: they stay in flight under A's compute
    float4 xb[4];
    if (hasB) {
        const float* arowB = attn + (size_t)urowB * S_LEN;
        #pragma unroll
        for (int k = 0; k < 4; ++k)
            xb[k] = *reinterpret_cast<const float4*>(arowB + k * 256 + 4 * lane);
    }

    // (4) compute + store row A (~800 cyc) while B's loads fly
    process_row(xa, packedA, out + (size_t)urowA * S_LEN, lane);

    // (5) GEMV B — its final vmcnt(0) drains B's attn loads exactly when needed
    if (hasB) {
        const int packedB = gemv_packed(query, pe, urowB, lane);
        process_row(xb, packedB, out + (size_t)urowB * S_LEN, lane);
    }
}

extern "C" void kernel_launch(void* const* d_in, const int* in_sizes, int n_in,
                              void* d_out, int out_size, void* d_ws, size_t ws_size,
                              hipStream_t stream) {
    const float* attn  = (const float*)d_in[0];   // [B,H,S,S] f32
    const float* query = (const float*)d_in[1];   // [B,H,S,D] f32
    const float* pe    = (const float*)d_in[2];   // [1,D,NPOS] f32
    float* out = (float*)d_out;                   // [B,H,S,S] f32

    const int rows   = in_sizes[0] / S_LEN;       // B*H*S = 49152
    const int waves  = (rows + 1) / 2;            // 2 rows per wave
    const int blocks = (waves + 3) / 4;           // 4 waves per block
    cope_kernel<<<blocks, 256, 0, stream>>>(attn, query, pe, out, rows);
}